// Round 2
// baseline (229.783 us; speedup 1.0000x reference)
//
#include <hip/hip_runtime.h>
#include <stdint.h>
#include <math.h>

#define D 2048
#define E 64
#define BM 32
#define BK 64
#define NCHUNK (D / BK)   // 32
#define NBLOCK 512        // 16384 rows / BM

typedef const __attribute__((address_space(1))) unsigned int guint;
typedef __attribute__((address_space(3))) unsigned int luint;

__device__ __forceinline__ void gl_lds16(const float* g, float* l) {
    __builtin_amdgcn_global_load_lds((guint*)g, (luint*)l, 16, 0, 0);
}

__global__ __launch_bounds__(256, 2)
void router_kernel(const float* __restrict__ x, const float* __restrict__ Wr,
                   float* __restrict__ out) {
    // Even k-quads of each W chunk, packed: WS[e][j], j = 4*qq + (k&3),
    // stored float index = e*32 + (j ^ ((e&7)<<2)).  8 KB per buffer.
    __shared__ float WS[2][E * 32];

    const int tid  = threadIdx.x;
    const int lane = tid & 63;
    const int w    = tid >> 6;
    const int wu   = __builtin_amdgcn_readfirstlane(w);   // wave-uniform wave id
    const int row0 = blockIdx.x * BM + wu * 8;            // wave-uniform

    // ---- staging precompute: thread t, inst i -> LDS float off = i*1024 + t*4
    // (linear dest, wave-uniform base + lane*16B; source pre-swizzled)
    int st_e[2], st_k8[2];
#pragma unroll
    for (int i = 0; i < 2; ++i) {
        const int off = i * 1024 + tid * 4;
        const int e   = off >> 5;           // expert
        const int j0  = off & 31;           // packed offset (multiple of 4)
        const int jsw = j0 ^ ((e & 7) << 2);
        st_e[i]  = e;
        st_k8[i] = 8 * (jsw >> 2);          // chunk-k of packed quad (even quads)
    }

#define STAGE(buf, kb) do {                                              \
        _Pragma("unroll")                                                \
        for (int i = 0; i < 2; ++i)                                      \
            gl_lds16(Wr + (size_t)st_e[i] * D + (kb) + st_k8[i],         \
                     &WS[buf][i * 1024 + tid * 4]);                      \
    } while (0)

    // wave-uniform x row pointers -> scalar (SMEM) loads
    const float* xr[8];
#pragma unroll
    for (int r = 0; r < 8; ++r) xr[r] = x + (size_t)(row0 + r) * D;

    const float* wg  = Wr + (size_t)lane * D;   // per-lane W row (global/L1 path)
    const int    ksw = (lane & 7) << 2;

    float acc[8];
#pragma unroll
    for (int r = 0; r < 8; ++r) acc[r] = 0.0f;

    STAGE(0, 0);
    asm volatile("s_waitcnt vmcnt(0)" ::: "memory");
    __syncthreads();

    int cur = 0;
    for (int c = 0; c < NCHUNK; ++c) {
        const int kb = c * BK;
        if (c + 1 < NCHUNK) STAGE(cur ^ 1, kb + BK);

        const float* wl = &WS[cur][lane * 32];
#pragma unroll
        for (int qq = 0; qq < 8; ++qq) {
            // W[lane][kb+8qq .. kb+8qq+3] from LDS (swizzled, conflict-spread)
            const float4 wv0 = *(const float4*)(wl + ((4 * qq) ^ ksw));
            // W[lane][kb+8qq+4 .. +7] from global (L2/L1-resident)
            const float4 wv1 = *(const float4*)(wg + kb + 8 * qq + 4);
#pragma unroll
            for (int r = 0; r < 8; ++r) {
                const float4 xa = *(const float4*)(xr[r] + kb + 8 * qq);     // uniform -> s_load
                const float4 xb = *(const float4*)(xr[r] + kb + 8 * qq + 4); // uniform -> s_load
                acc[r] = fmaf(xa.x, wv0.x, acc[r]);
                acc[r] = fmaf(xa.y, wv0.y, acc[r]);
                acc[r] = fmaf(xa.z, wv0.z, acc[r]);
                acc[r] = fmaf(xa.w, wv0.w, acc[r]);
                acc[r] = fmaf(xb.x, wv1.x, acc[r]);
                acc[r] = fmaf(xb.y, wv1.y, acc[r]);
                acc[r] = fmaf(xb.z, wv1.z, acc[r]);
                acc[r] = fmaf(xb.w, wv1.w, acc[r]);
            }
        }
        __syncthreads();
        cur ^= 1;
    }

    // ---- epilogue: softmax + top-2 per row (cross-lane over 64 experts) ----
    float* const out_gw    = out;               // [16384][2]
    float* const out_idx   = out + 32768;       // [16384][2] (indices as floats)
    float* const out_probs = out + 65536;       // [16384][64]

#pragma unroll 1
    for (int r = 0; r < 8; ++r) {
        const int row = row0 + r;
        const float v = acc[r];

        float m = v;
#pragma unroll
        for (int off = 32; off; off >>= 1) m = fmaxf(m, __shfl_xor(m, off));
        const float p = __expf(v - m);
        float s = p;
#pragma unroll
        for (int off = 32; off; off >>= 1) s += __shfl_xor(s, off);
        const float inv_s = 1.0f / s;

        out_probs[(size_t)row * 64 + lane] = p * inv_s;

        // top-1 (ties -> lower index, matching lax.top_k)
        float v1 = v; int i1 = lane;
#pragma unroll
        for (int off = 32; off; off >>= 1) {
            const float ov = __shfl_xor(v1, off);
            const int   oi = __shfl_xor(i1, off);
            if (ov > v1 || (ov == v1 && oi < i1)) { v1 = ov; i1 = oi; }
        }
        // top-2: mask out winner
        float v2 = (lane == i1) ? -INFINITY : v; int i2 = lane;
#pragma unroll
        for (int off = 32; off; off >>= 1) {
            const float ov = __shfl_xor(v2, off);
            const int   oi = __shfl_xor(i2, off);
            if (ov > v2 || (ov == v2 && oi < i2)) { v2 = ov; i2 = oi; }
        }

        if (lane == 0) {
            const float p1 = __expf(v1 - m) * inv_s;
            const float p2 = __expf(v2 - m) * inv_s;
            const float inv12 = 1.0f / (p1 + p2);
            out_gw[(size_t)row * 2 + 0]  = p1 * inv12;
            out_gw[(size_t)row * 2 + 1]  = p2 * inv12;
            out_idx[(size_t)row * 2 + 0] = (float)i1;
            out_idx[(size_t)row * 2 + 1] = (float)i2;
        }
    }
#undef STAGE
}

extern "C" void kernel_launch(void* const* d_in, const int* in_sizes, int n_in,
                              void* d_out, int out_size, void* d_ws, size_t ws_size,
                              hipStream_t stream) {
    const float* x  = (const float*)d_in[0];
    const float* Wr = (const float*)d_in[1];
    float* out = (float*)d_out;
    hipLaunchKernelGGL(router_kernel, dim3(NBLOCK), dim3(256), 0, stream, x, Wr, out);
}

// Round 3
// 112.072 us; speedup vs baseline: 2.0503x; 2.0503x over previous
//
#include <hip/hip_runtime.h>
#include <stdint.h>
#include <math.h>

#define D    2048
#define E    64
#define ROWS 16384
#define RG   64          // rows per block (lane = row)
#define BK   64          // k per chunk
#define EW   16          // experts per wave

typedef const __attribute__((address_space(1))) unsigned int guint;
typedef __attribute__((address_space(3))) unsigned int luint;
typedef __attribute__((ext_vector_type(16))) float f32x16;

__device__ __forceinline__ void gl_lds16(const float* g, float* l) {
    __builtin_amdgcn_global_load_lds((guint*)g, (luint*)l, 16, 0, 0);
}

// ---------------- kernel 1: logits partials ----------------
// grid = 256 row-groups x NSPLIT k-splits, 256 threads (4 waves).
// Wave w handles experts w*16..w*16+15 for all 64 rows (lane = row).
// X: staged to LDS (quad-swizzled) -> per-lane ds_read_b128.
// W: wave-uniform -> s_load_dwordx16, consumed as SGPR operand of v_fmac.
template<int NSPLIT>
__global__ __launch_bounds__(256, 4)
void logits_kernel(const float* __restrict__ x, const float* __restrict__ Wr,
                   float* __restrict__ P) {
    __shared__ float XS[2][RG * BK];   // 16 KB each

    const int tid  = threadIdx.x;
    const int lane = tid & 63;
    const int wu   = __builtin_amdgcn_readfirstlane(tid >> 6);
    const int bid  = blockIdx.x;
    const int ks   = bid % NSPLIT;
    const int rg   = bid / NSPLIT;
    const int row0 = rg * RG;
    const int kbase = ks * (D / NSPLIT);
    const int NCH  = (D / NSPLIT) / BK;

    // staging: thread t, inst i: dest float off = i*1024 + t*4 (linear, lane*16B)
    // dest row = i*16 + (t>>4); dest quad q = t&15 holds source quad q ^ (row&7)
    const float* xg[4];
#pragma unroll
    for (int i = 0; i < 4; ++i) {
        const int row = i * 16 + (tid >> 4);
        const int kq  = ((tid & 15) ^ (row & 7)) * 4;
        xg[i] = x + (size_t)(row0 + row) * D + kbase + kq;
    }
    float* const xsl0 = &XS[0][tid * 4];
    float* const xsl1 = &XS[1][tid * 4];

#define STAGE(buf, kc) do {                                                   \
        _Pragma("unroll")                                                     \
        for (int i = 0; i < 4; ++i)                                           \
            gl_lds16(xg[i] + (kc) * BK, ((buf) ? xsl1 : xsl0) + i * 1024);    \
    } while (0)

    const int eb = wu * EW;                       // wave-uniform expert base
    const float* const wbase = Wr + (size_t)eb * D + kbase;

    float acc[EW];
#pragma unroll
    for (int e = 0; e < EW; ++e) acc[e] = 0.0f;

    STAGE(0, 0);
    __syncthreads();

    const int swf = (lane & 7) * 4;               // read-side quad swizzle
    int cur = 0;
    for (int c = 0; c < NCH; ++c) {
        if (c + 1 < NCH) STAGE(cur ^ 1, c + 1);

        // this lane's row: 64 floats via 16 swizzled b128 (even 8-per-bank)
        float4 xv[16];
        const float* xr = &XS[cur][lane * BK];
#pragma unroll
        for (int q = 0; q < 16; ++q)
            xv[q] = *(const float4*)(xr + ((q * 4) ^ swf));

#pragma unroll
        for (int e = 0; e < EW; ++e) {
            const float* wr_ = wbase + (size_t)e * D + c * BK;   // uniform
#pragma unroll
            for (int g = 0; g < 4; ++g) {
                const f32x16 wv = *(const f32x16*)(wr_ + g * 16); // s_load_dwordx16
#pragma unroll
                for (int j = 0; j < 4; ++j) {
                    const float4 xq = xv[g * 4 + j];
                    acc[e] = fmaf(xq.x, wv[j * 4 + 0], acc[e]);
                    acc[e] = fmaf(xq.y, wv[j * 4 + 1], acc[e]);
                    acc[e] = fmaf(xq.z, wv[j * 4 + 2], acc[e]);
                    acc[e] = fmaf(xq.w, wv[j * 4 + 3], acc[e]);
                }
            }
        }
        __syncthreads();
        cur ^= 1;
    }

    // partial store: P[ks][row][e]
    float* const pr = P + ((size_t)ks * ROWS + row0 + lane) * E + eb;
#pragma unroll
    for (int e = 0; e < EW; ++e) pr[e] = acc[e];
#undef STAGE
}

// ---------------- kernel 2: reduce + softmax + top-2 ----------------
// 1 wave per row, lane = expert. Coalesced partial reads.
template<int NSPLIT>
__global__ __launch_bounds__(256, 8)
void finish_kernel(const float* __restrict__ P, float* __restrict__ out) {
    const int lane = threadIdx.x & 63;
    const int w    = threadIdx.x >> 6;
    const int row  = blockIdx.x * 4 + w;

    float v = 0.0f;
#pragma unroll
    for (int s = 0; s < NSPLIT; ++s)
        v += P[((size_t)s * ROWS + row) * E + lane];

    float* const out_gw    = out;               // [16384][2]
    float* const out_idx   = out + 32768;       // [16384][2] (indices as floats)
    float* const out_probs = out + 65536;       // [16384][64]

    float m = v;
#pragma unroll
    for (int off = 32; off; off >>= 1) m = fmaxf(m, __shfl_xor(m, off));
    const float p = __expf(v - m);
    float s = p;
#pragma unroll
    for (int off = 32; off; off >>= 1) s += __shfl_xor(s, off);
    const float inv_s = 1.0f / s;

    out_probs[(size_t)row * 64 + lane] = p * inv_s;

    // top-1 (ties -> lower index, matching lax.top_k)
    float v1 = v; int i1 = lane;
#pragma unroll
    for (int off = 32; off; off >>= 1) {
        const float ov = __shfl_xor(v1, off);
        const int   oi = __shfl_xor(i1, off);
        if (ov > v1 || (ov == v1 && oi < i1)) { v1 = ov; i1 = oi; }
    }
    // top-2: mask out winner
    float v2 = (lane == i1) ? -INFINITY : v; int i2 = lane;
#pragma unroll
    for (int off = 32; off; off >>= 1) {
        const float ov = __shfl_xor(v2, off);
        const int   oi = __shfl_xor(i2, off);
        if (ov > v2 || (ov == v2 && oi < i2)) { v2 = ov; i2 = oi; }
    }

    if (lane == 0) {
        const float p1 = __expf(v1 - m) * inv_s;
        const float p2 = __expf(v2 - m) * inv_s;
        const float inv12 = 1.0f / (p1 + p2);
        out_gw[(size_t)row * 2 + 0]  = p1 * inv12;
        out_gw[(size_t)row * 2 + 1]  = p2 * inv12;
        out_idx[(size_t)row * 2 + 0] = (float)i1;
        out_idx[(size_t)row * 2 + 1] = (float)i2;
    }
}

extern "C" void kernel_launch(void* const* d_in, const int* in_sizes, int n_in,
                              void* d_out, int out_size, void* d_ws, size_t ws_size,
                              hipStream_t stream) {
    const float* x  = (const float*)d_in[0];
    const float* Wr = (const float*)d_in[1];
    float* out = (float*)d_out;
    float* P   = (float*)d_ws;

    const size_t need4 = (size_t)4 * ROWS * E * sizeof(float);   // 16.8 MB
    if (ws_size >= need4) {
        hipLaunchKernelGGL((logits_kernel<4>), dim3(256 * 4), dim3(256), 0, stream, x, Wr, P);
        hipLaunchKernelGGL((finish_kernel<4>), dim3(ROWS / 4), dim3(256), 0, stream, P, out);
    } else {
        hipLaunchKernelGGL((logits_kernel<1>), dim3(256), dim3(256), 0, stream, x, Wr, P);
        hipLaunchKernelGGL((finish_kernel<1>), dim3(ROWS / 4), dim3(256), 0, stream, P, out);
    }
}